// Round 13
// baseline (117.223 us; speedup 1.0000x reference)
//
#include <hip/hip_runtime.h>

#define D1 96
#define GRID_VOX (D1 * D1 * D1)
#define CAP1 32   // per-voxel conv1 pairs (max 26 exact)
#define CAP2S 8   // per-(voxel,s) conv2 pairs (max 7 exact)

typedef __attribute__((ext_vector_type(8))) short short8_t;  // 8 bf16
typedef __attribute__((ext_vector_type(4))) float f32x4;

__device__ __forceinline__ unsigned short bf16rne(float x) {
    unsigned u = __float_as_uint(x);
    return (unsigned short)((u + 0x7FFF + ((u >> 16) & 1)) >> 16);
}
__device__ __forceinline__ void split2(float v, unsigned short& hi,
                                       unsigned short& lo) {
    hi = bf16rne(v);
    float hf = __uint_as_float((unsigned)hi << 16);
    lo = bf16rne(v - hf);
}
__device__ __forceinline__ float silu(float v) {
    return v / (1.f + __expf(-v));
}

// ---------------------------------------------------------------------------
// setup: blocks [0,432) zero grid; blocks [432,1474) pack MFMA B-fragments
// (bf16 hi/lo) and fold fp32 fixup weights.
// ---------------------------------------------------------------------------
__global__ void setup_kernel(const float* __restrict__ W1,
                             const float* __restrict__ W2,
                             int4* __restrict__ grid16,
                             unsigned short* __restrict__ Wpk1h,
                             unsigned short* __restrict__ Wpk1l,
                             unsigned short* __restrict__ Wpk2h,
                             unsigned short* __restrict__ Wpk2l,
                             float* __restrict__ W2e) {
    int b = blockIdx.x;
    if (b < 432) {
        grid16[b * 256 + threadIdx.x] = make_int4(0, 0, 0, 0);
        return;
    }
    int t = (b - 432) * 256 + threadIdx.x;
    if (t < 512) {  // conv1 B-fragments: W1[13] self tap
        int fid = t >> 6, l = t & 63;
        int kb = fid >> 2, c = fid & 3;
#pragma unroll
        for (int e = 0; e < 8; ++e) {
            int ci = kb * 32 + ((l >> 4) << 3) + e;
            int co = c * 16 + (l & 15);
            unsigned short hi, lo;
            split2(W1[13 * 4096 + ci * 64 + co], hi, lo);
            Wpk1h[(size_t)t * 8 + e] = hi;
            Wpk1l[(size_t)t * 8 + e] = lo;
        }
    } else if (t < 512 + 4096) {  // conv2 dense (self-parent fold) fragments
        int u = t - 512;
        int fid = u >> 6, l = u & 63;
        int s = fid >> 3, kb = (fid >> 2) & 1, c = fid & 3;
        int s0 = (s >> 2) & 1, s1 = (s >> 1) & 1, s2 = s & 1;
#pragma unroll
        for (int e = 0; e < 8; ++e) {
            int ci = kb * 32 + ((l >> 4) << 3) + e;
            int co = c * 16 + (l & 15);
            float sum = 0.f;
            for (int o0 = -s0; o0 <= 1 - s0; ++o0)
                for (int o1 = -s1; o1 <= 1 - s1; ++o1)
                    for (int o2 = -s2; o2 <= 1 - s2; ++o2) {
                        int k = (o0 + 1) * 9 + (o1 + 1) * 3 + (o2 + 1);
                        sum += W2[k * 4096 + ci * 64 + co];
                    }
            unsigned short hi, lo;
            split2(sum, hi, lo);
            Wpk2h[(size_t)u * 8 + e] = hi;
            Wpk2l[(size_t)u * 8 + e] = lo;
        }
    } else {  // W2e fp32 fixup weights
        int r = t - 4608;
        if (r >= 64 * 4096) return;
        int sd = r >> 12, e = r & 4095;
        int s = sd >> 3, d = sd & 7;
        int sa[3] = { (s >> 2) & 1, (s >> 1) & 1, s & 1 };
        int da[3] = { (d >> 2) & 1, (d >> 1) & 1, d & 1 };
        int lo_[3], hi_[3];
        for (int a = 0; a < 3; ++a) {
            int p = sa[a] - 1 + da[a];
            int l = 2 * p - sa[a];     if (l < -1) l = -1;
            int h = 2 * p + 1 - sa[a]; if (h > 1) h = 1;
            lo_[a] = l; hi_[a] = h;
        }
        float sum = 0.f;
        for (int o0 = lo_[0]; o0 <= hi_[0]; ++o0)
            for (int o1 = lo_[1]; o1 <= hi_[1]; ++o1)
                for (int o2 = lo_[2]; o2 <= hi_[2]; ++o2) {
                    int k = (o0 + 1) * 9 + (o1 + 1) * 3 + (o2 + 1);
                    sum += W2[k * 4096 + e];
                }
        W2e[(size_t)sd * 4096 + e] = sum;
    }
}

// ---------------------------------------------------------------------------
__global__ void scatter_grid_kernel(const int* __restrict__ coords,
                                    unsigned short* __restrict__ grid, int n) {
    int i = blockIdx.x * blockDim.x + threadIdx.x;
    if (i < n)
        grid[(coords[3 * i] * D1 + coords[3 * i + 1]) * D1 + coords[3 * i + 2]] =
            (unsigned short)(i + 1);
}

// ---------------------------------------------------------------------------
// Per-voxel pair builder (no atomics). conv1: j|(k<<17); conv2: j|(d<<17).
// ---------------------------------------------------------------------------
__global__ void build_pairs_kernel(const int* __restrict__ coords,
                                   const unsigned short* __restrict__ grid,
                                   int* __restrict__ c1, int* __restrict__ p1,
                                   int* __restrict__ c2s, int* __restrict__ p2s,
                                   int n) {
    int i = blockIdx.x * blockDim.x + threadIdx.x;
    if (i >= n) return;
    int c0 = coords[3 * i], cc1 = coords[3 * i + 1], cc2 = coords[3 * i + 2];

    int jv[27];
#pragma unroll
    for (int k = 0; k < 27; ++k) {
        int o0 = k / 9 - 1, o1 = (k / 3) % 3 - 1, o2 = k % 3 - 1;
        int x0 = c0 + o0, x1 = cc1 + o1, x2 = cc2 + o2;
        bool inb = (unsigned)x0 < D1 && (unsigned)x1 < D1 && (unsigned)x2 < D1;
        jv[k] = inb ? (int)grid[(x0 * D1 + x1) * D1 + x2] - 1 : -1;
    }

    int n1 = 0;
    int n2[8] = {0, 0, 0, 0, 0, 0, 0, 0};
#pragma unroll
    for (int k = 0; k < 27; ++k) {
        if (k == 13) continue;
        int j = jv[k];
        if (j < 0) continue;
        int o0 = k / 9 - 1, o1 = (k / 3) % 3 - 1, o2 = k % 3 - 1;
        p1[(size_t)i * CAP1 + n1] = j | (k << 17);
        ++n1;
#pragma unroll
        for (int s = 0; s < 8; ++s) {
            int d0 = o0 + 1 - ((s >> 2) & 1);
            int d1 = o1 + 1 - ((s >> 1) & 1);
            int d2 = o2 + 1 - (s & 1);
            if (((d0 | d1 | d2) & ~1) == 0) {
                int d = (d0 << 2) | (d1 << 1) | d2;
                p2s[((size_t)i * 8 + s) * CAP2S + n2[s]] = j | (d << 17);
                ++n2[s];
            }
        }
    }
    c1[i] = n1;
#pragma unroll
    for (int s = 0; s < 8; ++s) c2s[i * 8 + s] = n2[s];
}

// ---------------------------------------------------------------------------
__device__ __forceinline__ void load_split_A(const float* __restrict__ src,
                                             int arow, int lane, short8_t& ah0,
                                             short8_t& al0, short8_t& ah1,
                                             short8_t& al1) {
    const float* ap = src + (size_t)arow * 64 + ((lane >> 4) << 3);
    f32x4 a0 = *(const f32x4*)(ap);
    f32x4 a1 = *(const f32x4*)(ap + 4);
    f32x4 a2 = *(const f32x4*)(ap + 32);
    f32x4 a3 = *(const f32x4*)(ap + 36);
#pragma unroll
    for (int e = 0; e < 4; ++e) {
        unsigned short hh, ll;
        split2(a0[e], hh, ll); ah0[e] = (short)hh; al0[e] = (short)ll;
        split2(a1[e], hh, ll); ah0[4 + e] = (short)hh; al0[4 + e] = (short)ll;
        split2(a2[e], hh, ll); ah1[e] = (short)hh; al1[e] = (short)ll;
        split2(a3[e], hh, ll); ah1[4 + e] = (short)hh; al1[4 + e] = (short)ll;
    }
}

// ---------------------------------------------------------------------------
// wave w: rows [16w,16w+16) x 64 cols, 24 MFMAs (hi/lo), +bias -> oT.
// ---------------------------------------------------------------------------
__device__ __forceinline__ void dense_mfma(const short8_t ah0, const short8_t al0,
                                           const short8_t ah1, const short8_t al1,
                                           const short8_t* __restrict__ Bh,
                                           const short8_t* __restrict__ Bl,
                                           const float* __restrict__ bias,
                                           float* __restrict__ oT, int w,
                                           int lane) {
#pragma unroll 1
    for (int c = 0; c < 4; ++c) {
        short8_t bh0 = Bh[c * 64 + lane];
        short8_t bl0 = Bl[c * 64 + lane];
        short8_t bh1 = Bh[(4 + c) * 64 + lane];
        short8_t bl1 = Bl[(4 + c) * 64 + lane];
        f32x4 acc = {0.f, 0.f, 0.f, 0.f};
        acc = __builtin_amdgcn_mfma_f32_16x16x32_bf16(ah0, bh0, acc, 0, 0, 0);
        acc = __builtin_amdgcn_mfma_f32_16x16x32_bf16(al0, bh0, acc, 0, 0, 0);
        acc = __builtin_amdgcn_mfma_f32_16x16x32_bf16(ah0, bl0, acc, 0, 0, 0);
        acc = __builtin_amdgcn_mfma_f32_16x16x32_bf16(ah1, bh1, acc, 0, 0, 0);
        acc = __builtin_amdgcn_mfma_f32_16x16x32_bf16(al1, bh1, acc, 0, 0, 0);
        acc = __builtin_amdgcn_mfma_f32_16x16x32_bf16(ah1, bl1, acc, 0, 0, 0);
        int col = c * 16 + (lane & 15);
        float bb = bias[col];
#pragma unroll
        for (int r = 0; r < 4; ++r) {
            int row = w * 16 + ((lane >> 4) << 2) + r;
            oT[row * 64 + col] = acc[r] + bb;
        }
    }
}

// wave-scan helper (t<64): counts -> excl prefix + total, stored in LDS
__device__ __forceinline__ void scan64(int cnt, int lane, int* pfxs, int* cnts,
                                       int* nps) {
    int val = cnt;
#pragma unroll
    for (int off = 1; off < 64; off <<= 1) {
        int v2 = __shfl_up(val, off);
        if (lane >= off) val += v2;
    }
    pfxs[lane] = val - cnt;
    cnts[lane] = cnt;
    if (lane == 63) nps[0] = val;
}

// Process one bin's pairs with weight column held in VGPRs.
// wk = weight base [ci][co]; pls = sorted entries; feature src.
__device__ __forceinline__ void bin_fixups(const float* __restrict__ src,
                                           const float* __restrict__ wk,
                                           const int* __restrict__ pls, int s0,
                                           int s1, float* __restrict__ oT,
                                           int lane) {
    float wreg[64];
#pragma unroll
    for (int ci = 0; ci < 64; ++ci) wreg[ci] = wk[ci * 64 + lane];

    int e = pls[s0];
    float fv = src[(size_t)(e & 0x1FFFF) * 64 + lane];
#pragma unroll 1
    for (int p = s0; p < s1; ++p) {
        int en = 0;
        float fvn = 0.f;
        if (p + 1 < s1) {  // prefetch next pair's feature row
            en = pls[p + 1];
            fvn = src[(size_t)(en & 0x1FFFF) * 64 + lane];
        }
        int row = (e >> 23) & 63;
        float a0 = 0.f, a1 = 0.f, a2 = 0.f, a3 = 0.f;
#pragma unroll
        for (int ci = 0; ci < 64; ci += 4) {
            a0 += __shfl(fv, ci + 0) * wreg[ci + 0];
            a1 += __shfl(fv, ci + 1) * wreg[ci + 1];
            a2 += __shfl(fv, ci + 2) * wreg[ci + 2];
            a3 += __shfl(fv, ci + 3) * wreg[ci + 3];
        }
        atomicAdd(&oT[row * 64 + lane], (a0 + a1) + (a2 + a3));
        e = en;
        fv = fvn;
    }
}

// ---------------------------------------------------------------------------
// conv1 fused: dense MFMA -> compact -> counting-sort by k -> per-bin
// register-weight fixups -> SiLU.
// ---------------------------------------------------------------------------
__global__ __launch_bounds__(256) void conv1_fused_kernel(
    const float* __restrict__ feats, const float* __restrict__ W1,
    const unsigned short* __restrict__ Wpk1h,
    const unsigned short* __restrict__ Wpk1l, const float* __restrict__ b1,
    const int* __restrict__ c1, const int* __restrict__ p1,
    float* __restrict__ h, int n) {
    __shared__ __align__(16) float oT[4096];
    __shared__ int pl[1664], pls[1664];
    __shared__ int pfxs[64], cnts_s[64], nps[1];
    __shared__ int binStart[29], binCur[28];
    int base = blockIdx.x * 64;
    int t = threadIdx.x, w = t >> 6, lane = t & 63;

    if (t < 64) {
        int cnt = (base + lane < n) ? c1[base + lane] : 0;
        scan64(cnt, lane, pfxs, cnts_s, nps);
    }
    if (t >= 64 && t < 92) binCur[t - 64] = 0;

    int arow = base + w * 16 + (lane & 15);
    if (arow >= n) arow = n - 1;
    short8_t ah0, al0, ah1, al1;
    load_split_A(feats, arow, lane, ah0, al0, ah1, al1);
    dense_mfma(ah0, al0, ah1, al1, (const short8_t*)Wpk1h,
               (const short8_t*)Wpk1l, b1, oT, w, lane);
    __syncthreads();

    {   // parallel compaction: 4 threads per row
        int row = t & 63, e0 = t >> 6;
        int cr = cnts_s[row], pf = pfxs[row];
        for (int e = e0; e < cr; e += 4)
            pl[pf + e] = p1[(size_t)(base + row) * CAP1 + e] | (row << 23);
    }
    __syncthreads();

    int np = nps[0];
    // counting sort by k (bins 0..27)
    for (int p = t; p < np; p += 256) atomicAdd(&binCur[(pl[p] >> 17) & 31], 1);
    __syncthreads();
    if (t == 0) {
        int acc = 0;
        for (int b = 0; b < 28; ++b) {
            binStart[b] = acc;
            acc += binCur[b];
        }
        binStart[28] = acc;
    }
    __syncthreads();
    if (t < 28) binCur[t] = binStart[t];
    __syncthreads();
    for (int p = t; p < np; p += 256) {
        int e = pl[p];
        int dst = atomicAdd(&binCur[(e >> 17) & 31], 1);
        pls[dst] = e;
    }
    __syncthreads();

    // per-bin fixups, bins striped over waves
#pragma unroll 1
    for (int b = w; b < 28; b += 4) {
        int s0 = binStart[b], s1 = binStart[b + 1];
        if (s0 == s1) continue;
        bin_fixups(feats, W1 + (size_t)b * 4096, pls, s0, s1, oT, lane);
    }
    __syncthreads();

    {   // SiLU + coalesced store
        int r = t >> 2, q0 = (t & 3) * 16;
        if (base + r < n) {
#pragma unroll
            for (int jj = 0; jj < 4; ++jj) {
                f32x4 v = *(f32x4*)&oT[r * 64 + q0 + jj * 4];
#pragma unroll
                for (int u = 0; u < 4; ++u) v[u] = silu(v[u]);
                *(f32x4*)&h[(size_t)(base + r) * 64 + q0 + jj * 4] = v;
            }
        }
    }
}

// ---------------------------------------------------------------------------
// conv2 fused: grid (313, 8). Same structure; 8 d-bins.
// ---------------------------------------------------------------------------
__global__ __launch_bounds__(256) void conv2_fused_kernel(
    const float* __restrict__ h, const unsigned short* __restrict__ Wpk2h,
    const unsigned short* __restrict__ Wpk2l, const float* __restrict__ W2e,
    const float* __restrict__ b2, const int* __restrict__ c2s,
    const int* __restrict__ p2s, float* __restrict__ out, int n) {
    __shared__ __align__(16) float oT[4096];
    __shared__ int pl[448], pls[448];
    __shared__ int pfxs[64], cnts_s[64], nps[1];
    __shared__ int binStart[9], binCur[8];
    int base = blockIdx.x * 64, s = blockIdx.y;
    int t = threadIdx.x, w = t >> 6, lane = t & 63;

    if (t < 64) {
        int cnt = (base + lane < n) ? c2s[(size_t)(base + lane) * 8 + s] : 0;
        scan64(cnt, lane, pfxs, cnts_s, nps);
    }
    if (t >= 64 && t < 72) binCur[t - 64] = 0;

    int arow = base + w * 16 + (lane & 15);
    if (arow >= n) arow = n - 1;
    short8_t ah0, al0, ah1, al1;
    load_split_A(h, arow, lane, ah0, al0, ah1, al1);
    dense_mfma(ah0, al0, ah1, al1,
               (const short8_t*)Wpk2h + (size_t)s * 8 * 64,
               (const short8_t*)Wpk2l + (size_t)s * 8 * 64, b2, oT, w, lane);
    __syncthreads();

    {   // parallel compaction
        int row = t & 63, e0 = t >> 6;
        int cr = cnts_s[row], pf = pfxs[row];
        for (int e = e0; e < cr; e += 4)
            pl[pf + e] =
                p2s[((size_t)(base + row) * 8 + s) * CAP2S + e] | (row << 23);
    }
    __syncthreads();

    int np = nps[0];
    for (int p = t; p < np; p += 256) atomicAdd(&binCur[(pl[p] >> 17) & 7], 1);
    __syncthreads();
    if (t == 0) {
        int acc = 0;
        for (int b = 0; b < 8; ++b) {
            binStart[b] = acc;
            acc += binCur[b];
        }
        binStart[8] = acc;
    }
    __syncthreads();
    if (t < 8) binCur[t] = binStart[t];
    __syncthreads();
    for (int p = t; p < np; p += 256) {
        int e = pl[p];
        int dst = atomicAdd(&binCur[(e >> 17) & 7], 1);
        pls[dst] = e;
    }
    __syncthreads();

#pragma unroll 1
    for (int b = w; b < 8; b += 4) {
        int s0 = binStart[b], s1 = binStart[b + 1];
        if (s0 == s1) continue;
        bin_fixups(h, W2e + (size_t)(s * 8 + b) * 4096, pls, s0, s1, oT, lane);
    }
    __syncthreads();

    {   // SiLU + store (out row = parent*8 + s)
        int r = t >> 2, q0 = (t & 3) * 16;
        if (base + r < n) {
#pragma unroll
            for (int jj = 0; jj < 4; ++jj) {
                f32x4 v = *(f32x4*)&oT[r * 64 + q0 + jj * 4];
#pragma unroll
                for (int u = 0; u < 4; ++u) v[u] = silu(v[u]);
                *(f32x4*)&out[((size_t)(base + r) * 8 + s) * 64 + q0 + jj * 4] = v;
            }
        }
    }
}

// ---------------------------------------------------------------------------
extern "C" void kernel_launch(void* const* d_in, const int* in_sizes, int n_in,
                              void* d_out, int out_size, void* d_ws,
                              size_t ws_size, hipStream_t stream) {
    const int* coords = (const int*)d_in[0];
    const float* feats = (const float*)d_in[1];
    const float* W1 = (const float*)d_in[2];
    const float* b1 = (const float*)d_in[3];
    const float* W2 = (const float*)d_in[4];
    const float* b2 = (const float*)d_in[5];
    float* out = (float*)d_out;

    int n = in_sizes[0] / 3;  // 20000
    int nblk = (n + 63) / 64; // 313

    char* ws = (char*)d_ws;
    size_t off = 0;
    auto alloc = [&](size_t bytes) {
        size_t o = off;
        off = (off + bytes + 255) & ~(size_t)255;
        return o;
    };
    unsigned short* grid1 = (unsigned short*)(ws + alloc((size_t)GRID_VOX * 2));
    float* h      = (float*)(ws + alloc((size_t)n * 64 * 4));     // 5.12 MB
    float* W2e    = (float*)(ws + alloc(64 * 4096 * 4));          // 1 MB
    unsigned short* Wpk1h = (unsigned short*)(ws + alloc(512 * 8 * 2));
    unsigned short* Wpk1l = (unsigned short*)(ws + alloc(512 * 8 * 2));
    unsigned short* Wpk2h = (unsigned short*)(ws + alloc(4096 * 8 * 2));
    unsigned short* Wpk2l = (unsigned short*)(ws + alloc(4096 * 8 * 2));
    int*   c1     = (int*)(ws + alloc((size_t)n * 9 * 4));        // c1[n]+c2s[8n]
    int*   c2s    = c1 + n;
    int*   p1     = (int*)(ws + alloc((size_t)n * CAP1 * 4));     // 2.56 MB
    int*   p2s    = (int*)(ws + alloc((size_t)n * 8 * CAP2S * 4)); // 5.12 MB

    setup_kernel<<<1474, 256, 0, stream>>>(W1, W2, (int4*)grid1, Wpk1h, Wpk1l,
                                           Wpk2h, Wpk2l, W2e);
    scatter_grid_kernel<<<(n + 255) / 256, 256, 0, stream>>>(coords, grid1, n);
    build_pairs_kernel<<<(n + 255) / 256, 256, 0, stream>>>(
        coords, grid1, c1, p1, c2s, p2s, n);

    conv1_fused_kernel<<<nblk, 256, 0, stream>>>(feats, W1, Wpk1h, Wpk1l, b1,
                                                 c1, p1, h, n);
    conv2_fused_kernel<<<dim3(nblk, 8), 256, 0, stream>>>(
        h, Wpk2h, Wpk2l, W2e, b2, c2s, p2s, out, n);
}

// Round 14
// 86.224 us; speedup vs baseline: 1.3595x; 1.3595x over previous
//
#include <hip/hip_runtime.h>

#define D1 96
#define GRID_VOX (D1 * D1 * D1)
#define CAP1 32   // per-voxel conv1 pairs (max 26 exact)
#define CAP2S 8   // per-(voxel,s) conv2 pairs (max 7 exact)

typedef __attribute__((ext_vector_type(8))) short short8_t;  // 8 bf16
typedef __attribute__((ext_vector_type(4))) float f32x4;

__device__ __forceinline__ unsigned short bf16rne(float x) {
    unsigned u = __float_as_uint(x);
    return (unsigned short)((u + 0x7FFF + ((u >> 16) & 1)) >> 16);
}
__device__ __forceinline__ void split2(float v, unsigned short& hi,
                                       unsigned short& lo) {
    hi = bf16rne(v);
    float hf = __uint_as_float((unsigned)hi << 16);
    lo = bf16rne(v - hf);
}
__device__ __forceinline__ float silu(float v) {
    return v / (1.f + __expf(-v));
}

// ---------------------------------------------------------------------------
// setup: blocks [0,432) zero grid; blocks [432,1474) pack MFMA B-fragments
// (bf16 hi/lo) and fold fp32 fixup weights.
// ---------------------------------------------------------------------------
__global__ void setup_kernel(const float* __restrict__ W1,
                             const float* __restrict__ W2,
                             int4* __restrict__ grid16,
                             unsigned short* __restrict__ Wpk1h,
                             unsigned short* __restrict__ Wpk1l,
                             unsigned short* __restrict__ Wpk2h,
                             unsigned short* __restrict__ Wpk2l,
                             float* __restrict__ W2e) {
    int b = blockIdx.x;
    if (b < 432) {
        grid16[b * 256 + threadIdx.x] = make_int4(0, 0, 0, 0);
        return;
    }
    int t = (b - 432) * 256 + threadIdx.x;
    if (t < 512) {  // conv1 B-fragments: W1[13] self tap
        int fid = t >> 6, l = t & 63;
        int kb = fid >> 2, c = fid & 3;
#pragma unroll
        for (int e = 0; e < 8; ++e) {
            int ci = kb * 32 + ((l >> 4) << 3) + e;
            int co = c * 16 + (l & 15);
            unsigned short hi, lo;
            split2(W1[13 * 4096 + ci * 64 + co], hi, lo);
            Wpk1h[(size_t)t * 8 + e] = hi;
            Wpk1l[(size_t)t * 8 + e] = lo;
        }
    } else if (t < 512 + 4096) {  // conv2 dense (self-parent fold) fragments
        int u = t - 512;
        int fid = u >> 6, l = u & 63;
        int s = fid >> 3, kb = (fid >> 2) & 1, c = fid & 3;
        int s0 = (s >> 2) & 1, s1 = (s >> 1) & 1, s2 = s & 1;
#pragma unroll
        for (int e = 0; e < 8; ++e) {
            int ci = kb * 32 + ((l >> 4) << 3) + e;
            int co = c * 16 + (l & 15);
            float sum = 0.f;
            for (int o0 = -s0; o0 <= 1 - s0; ++o0)
                for (int o1 = -s1; o1 <= 1 - s1; ++o1)
                    for (int o2 = -s2; o2 <= 1 - s2; ++o2) {
                        int k = (o0 + 1) * 9 + (o1 + 1) * 3 + (o2 + 1);
                        sum += W2[k * 4096 + ci * 64 + co];
                    }
            unsigned short hi, lo;
            split2(sum, hi, lo);
            Wpk2h[(size_t)u * 8 + e] = hi;
            Wpk2l[(size_t)u * 8 + e] = lo;
        }
    } else {  // W2e fp32 fixup weights
        int r = t - 4608;
        if (r >= 64 * 4096) return;
        int sd = r >> 12, e = r & 4095;
        int s = sd >> 3, d = sd & 7;
        int sa[3] = { (s >> 2) & 1, (s >> 1) & 1, s & 1 };
        int da[3] = { (d >> 2) & 1, (d >> 1) & 1, d & 1 };
        int lo_[3], hi_[3];
        for (int a = 0; a < 3; ++a) {
            int p = sa[a] - 1 + da[a];
            int l = 2 * p - sa[a];     if (l < -1) l = -1;
            int h = 2 * p + 1 - sa[a]; if (h > 1) h = 1;
            lo_[a] = l; hi_[a] = h;
        }
        float sum = 0.f;
        for (int o0 = lo_[0]; o0 <= hi_[0]; ++o0)
            for (int o1 = lo_[1]; o1 <= hi_[1]; ++o1)
                for (int o2 = lo_[2]; o2 <= hi_[2]; ++o2) {
                    int k = (o0 + 1) * 9 + (o1 + 1) * 3 + (o2 + 1);
                    sum += W2[k * 4096 + e];
                }
        W2e[(size_t)sd * 4096 + e] = sum;
    }
}

// ---------------------------------------------------------------------------
__global__ void scatter_grid_kernel(const int* __restrict__ coords,
                                    unsigned short* __restrict__ grid, int n) {
    int i = blockIdx.x * blockDim.x + threadIdx.x;
    if (i < n)
        grid[(coords[3 * i] * D1 + coords[3 * i + 1]) * D1 + coords[3 * i + 2]] =
            (unsigned short)(i + 1);
}

// ---------------------------------------------------------------------------
// Per-voxel pair builder (no atomics). conv1: j|(k<<17); conv2: j|(d<<17).
// ---------------------------------------------------------------------------
__global__ void build_pairs_kernel(const int* __restrict__ coords,
                                   const unsigned short* __restrict__ grid,
                                   int* __restrict__ c1, int* __restrict__ p1,
                                   int* __restrict__ c2s, int* __restrict__ p2s,
                                   int n) {
    int i = blockIdx.x * blockDim.x + threadIdx.x;
    if (i >= n) return;
    int c0 = coords[3 * i], cc1 = coords[3 * i + 1], cc2 = coords[3 * i + 2];

    int jv[27];
#pragma unroll
    for (int k = 0; k < 27; ++k) {
        int o0 = k / 9 - 1, o1 = (k / 3) % 3 - 1, o2 = k % 3 - 1;
        int x0 = c0 + o0, x1 = cc1 + o1, x2 = cc2 + o2;
        bool inb = (unsigned)x0 < D1 && (unsigned)x1 < D1 && (unsigned)x2 < D1;
        jv[k] = inb ? (int)grid[(x0 * D1 + x1) * D1 + x2] - 1 : -1;
    }

    int n1 = 0;
    int n2[8] = {0, 0, 0, 0, 0, 0, 0, 0};
#pragma unroll
    for (int k = 0; k < 27; ++k) {
        if (k == 13) continue;
        int j = jv[k];
        if (j < 0) continue;
        int o0 = k / 9 - 1, o1 = (k / 3) % 3 - 1, o2 = k % 3 - 1;
        p1[(size_t)i * CAP1 + n1] = j | (k << 17);
        ++n1;
#pragma unroll
        for (int s = 0; s < 8; ++s) {
            int d0 = o0 + 1 - ((s >> 2) & 1);
            int d1 = o1 + 1 - ((s >> 1) & 1);
            int d2 = o2 + 1 - (s & 1);
            if (((d0 | d1 | d2) & ~1) == 0) {
                int d = (d0 << 2) | (d1 << 1) | d2;
                p2s[((size_t)i * 8 + s) * CAP2S + n2[s]] = j | (d << 17);
                ++n2[s];
            }
        }
    }
    c1[i] = n1;
#pragma unroll
    for (int s = 0; s < 8; ++s) c2s[i * 8 + s] = n2[s];
}

// ---------------------------------------------------------------------------
__device__ __forceinline__ void load_split_A(const float* __restrict__ src,
                                             int arow, int lane, short8_t& ah0,
                                             short8_t& al0, short8_t& ah1,
                                             short8_t& al1) {
    const float* ap = src + (size_t)arow * 64 + ((lane >> 4) << 3);
    f32x4 a0 = *(const f32x4*)(ap);
    f32x4 a1 = *(const f32x4*)(ap + 4);
    f32x4 a2 = *(const f32x4*)(ap + 32);
    f32x4 a3 = *(const f32x4*)(ap + 36);
#pragma unroll
    for (int e = 0; e < 4; ++e) {
        unsigned short hh, ll;
        split2(a0[e], hh, ll); ah0[e] = (short)hh; al0[e] = (short)ll;
        split2(a1[e], hh, ll); ah0[4 + e] = (short)hh; al0[4 + e] = (short)ll;
        split2(a2[e], hh, ll); ah1[e] = (short)hh; al1[e] = (short)ll;
        split2(a3[e], hh, ll); ah1[4 + e] = (short)hh; al1[4 + e] = (short)ll;
    }
}

// ---------------------------------------------------------------------------
// wave w: rows [16w,16w+16) x 64 cols, 24 MFMAs (hi/lo), +bias -> oT.
// ---------------------------------------------------------------------------
__device__ __forceinline__ void dense_mfma(const short8_t ah0, const short8_t al0,
                                           const short8_t ah1, const short8_t al1,
                                           const short8_t* __restrict__ Bh,
                                           const short8_t* __restrict__ Bl,
                                           const float* __restrict__ bias,
                                           float* __restrict__ oT, int w,
                                           int lane) {
#pragma unroll 1
    for (int c = 0; c < 4; ++c) {
        short8_t bh0 = Bh[c * 64 + lane];
        short8_t bl0 = Bl[c * 64 + lane];
        short8_t bh1 = Bh[(4 + c) * 64 + lane];
        short8_t bl1 = Bl[(4 + c) * 64 + lane];
        f32x4 acc = {0.f, 0.f, 0.f, 0.f};
        acc = __builtin_amdgcn_mfma_f32_16x16x32_bf16(ah0, bh0, acc, 0, 0, 0);
        acc = __builtin_amdgcn_mfma_f32_16x16x32_bf16(al0, bh0, acc, 0, 0, 0);
        acc = __builtin_amdgcn_mfma_f32_16x16x32_bf16(ah0, bl0, acc, 0, 0, 0);
        acc = __builtin_amdgcn_mfma_f32_16x16x32_bf16(ah1, bh1, acc, 0, 0, 0);
        acc = __builtin_amdgcn_mfma_f32_16x16x32_bf16(al1, bh1, acc, 0, 0, 0);
        acc = __builtin_amdgcn_mfma_f32_16x16x32_bf16(ah1, bl1, acc, 0, 0, 0);
        int col = c * 16 + (lane & 15);
        float bb = bias[col];
#pragma unroll
        for (int r = 0; r < 4; ++r) {
            int row = w * 16 + ((lane >> 4) << 2) + r;
            oT[row * 64 + col] = acc[r] + bb;
        }
    }
}

// wave-scan helper (t<64): counts -> excl prefix + total, stored in LDS
__device__ __forceinline__ void scan64(int cnt, int lane, int* pfxs, int* cnts,
                                       int* nps) {
    int val = cnt;
#pragma unroll
    for (int off = 1; off < 64; off <<= 1) {
        int v2 = __shfl_up(val, off);
        if (lane >= off) val += v2;
    }
    pfxs[lane] = val - cnt;
    cnts[lane] = cnt;
    if (lane == 63) nps[0] = val;
}

// ---------------------------------------------------------------------------
// Barrier-free per-wave fixup loop: pairs striped over waves; each pair =
// coalesced feature-row load -> wave-private LDS scratch (double-buffered) ->
// 16 broadcast ds_reads + 16 coalesced weight vector loads -> LDS atomicAdd.
// ---------------------------------------------------------------------------
__device__ __forceinline__ void fixup_loop(const float* __restrict__ src,
                                           const float* __restrict__ Wbase,
                                           const int* __restrict__ pl, int np,
                                           float fsc[4][2][64],
                                           float* __restrict__ oT, int w,
                                           int lane) {
    int it = 0;
#pragma unroll 1
    for (int p = w; p < np; p += 4, ++it) {
        int e = pl[p];
        int j = e & 0x1FFFF, tag = (e >> 17) & 31, row = (e >> 23) & 63;
        float fv = src[(size_t)j * 64 + lane];  // coalesced 256B row
        int buf = it & 1;
        fsc[w][buf][lane] = fv;
        const float* wk = Wbase + (size_t)tag * 4096;  // [ci][co]
        float a0 = 0.f, a1 = 0.f, a2 = 0.f, a3 = 0.f;
#pragma unroll
        for (int c4 = 0; c4 < 16; ++c4) {
            f32x4 fb = *(f32x4*)&fsc[w][buf][c4 * 4];  // ds broadcast
            a0 += fb[0] * wk[(c4 * 4 + 0) * 64 + lane];
            a1 += fb[1] * wk[(c4 * 4 + 1) * 64 + lane];
            a2 += fb[2] * wk[(c4 * 4 + 2) * 64 + lane];
            a3 += fb[3] * wk[(c4 * 4 + 3) * 64 + lane];
        }
        atomicAdd(&oT[row * 64 + lane], (a0 + a1) + (a2 + a3));
    }
}

// ---------------------------------------------------------------------------
// conv1 fused: dense MFMA ∥ scan -> compact -> barrier-free fixups -> SiLU.
// ---------------------------------------------------------------------------
__global__ __launch_bounds__(256) void conv1_fused_kernel(
    const float* __restrict__ feats, const float* __restrict__ W1,
    const unsigned short* __restrict__ Wpk1h,
    const unsigned short* __restrict__ Wpk1l, const float* __restrict__ b1,
    const int* __restrict__ c1, const int* __restrict__ p1,
    float* __restrict__ h, int n) {
    __shared__ __align__(16) float oT[4096];
    __shared__ __align__(16) float fsc[4][2][64];
    __shared__ int pl[1664];
    __shared__ int pfxs[64], cnts_s[64], nps[1];
    int base = blockIdx.x * 64;
    int t = threadIdx.x, w = t >> 6, lane = t & 63;

    if (t < 64) {
        int cnt = (base + lane < n) ? c1[base + lane] : 0;
        scan64(cnt, lane, pfxs, cnts_s, nps);
    }

    int arow = base + w * 16 + (lane & 15);
    if (arow >= n) arow = n - 1;
    short8_t ah0, al0, ah1, al1;
    load_split_A(feats, arow, lane, ah0, al0, ah1, al1);
    dense_mfma(ah0, al0, ah1, al1, (const short8_t*)Wpk1h,
               (const short8_t*)Wpk1l, b1, oT, w, lane);
    __syncthreads();

    {   // parallel compaction: 4 threads per row
        int row = t & 63, e0 = t >> 6;
        int cr = cnts_s[row], pf = pfxs[row];
        for (int e = e0; e < cr; e += 4)
            pl[pf + e] = p1[(size_t)(base + row) * CAP1 + e] | (row << 23);
    }
    __syncthreads();

    fixup_loop(feats, W1, pl, nps[0], fsc, oT, w, lane);
    __syncthreads();

    {   // SiLU + coalesced store
        int r = t >> 2, q0 = (t & 3) * 16;
        if (base + r < n) {
#pragma unroll
            for (int jj = 0; jj < 4; ++jj) {
                f32x4 v = *(f32x4*)&oT[r * 64 + q0 + jj * 4];
#pragma unroll
                for (int u = 0; u < 4; ++u) v[u] = silu(v[u]);
                *(f32x4*)&h[(size_t)(base + r) * 64 + q0 + jj * 4] = v;
            }
        }
    }
}

// ---------------------------------------------------------------------------
// conv2 fused: grid (313, 8). Same structure.
// ---------------------------------------------------------------------------
__global__ __launch_bounds__(256) void conv2_fused_kernel(
    const float* __restrict__ h, const unsigned short* __restrict__ Wpk2h,
    const unsigned short* __restrict__ Wpk2l, const float* __restrict__ W2e,
    const float* __restrict__ b2, const int* __restrict__ c2s,
    const int* __restrict__ p2s, float* __restrict__ out, int n) {
    __shared__ __align__(16) float oT[4096];
    __shared__ __align__(16) float fsc[4][2][64];
    __shared__ int pl[448];
    __shared__ int pfxs[64], cnts_s[64], nps[1];
    int base = blockIdx.x * 64, s = blockIdx.y;
    int t = threadIdx.x, w = t >> 6, lane = t & 63;

    if (t < 64) {
        int cnt = (base + lane < n) ? c2s[(size_t)(base + lane) * 8 + s] : 0;
        scan64(cnt, lane, pfxs, cnts_s, nps);
    }

    int arow = base + w * 16 + (lane & 15);
    if (arow >= n) arow = n - 1;
    short8_t ah0, al0, ah1, al1;
    load_split_A(h, arow, lane, ah0, al0, ah1, al1);
    dense_mfma(ah0, al0, ah1, al1,
               (const short8_t*)Wpk2h + (size_t)s * 8 * 64,
               (const short8_t*)Wpk2l + (size_t)s * 8 * 64, b2, oT, w, lane);
    __syncthreads();

    {   // parallel compaction
        int row = t & 63, e0 = t >> 6;
        int cr = cnts_s[row], pf = pfxs[row];
        for (int e = e0; e < cr; e += 4)
            pl[pf + e] =
                p2s[((size_t)(base + row) * 8 + s) * CAP2S + e] | (row << 23);
    }
    __syncthreads();

    fixup_loop(h, W2e + (size_t)s * 8 * 4096, pl, nps[0], fsc, oT, w, lane);
    __syncthreads();

    {   // SiLU + store (out row = parent*8 + s)
        int r = t >> 2, q0 = (t & 3) * 16;
        if (base + r < n) {
#pragma unroll
            for (int jj = 0; jj < 4; ++jj) {
                f32x4 v = *(f32x4*)&oT[r * 64 + q0 + jj * 4];
#pragma unroll
                for (int u = 0; u < 4; ++u) v[u] = silu(v[u]);
                *(f32x4*)&out[((size_t)(base + r) * 8 + s) * 64 + q0 + jj * 4] = v;
            }
        }
    }
}

// ---------------------------------------------------------------------------
extern "C" void kernel_launch(void* const* d_in, const int* in_sizes, int n_in,
                              void* d_out, int out_size, void* d_ws,
                              size_t ws_size, hipStream_t stream) {
    const int* coords = (const int*)d_in[0];
    const float* feats = (const float*)d_in[1];
    const float* W1 = (const float*)d_in[2];
    const float* b1 = (const float*)d_in[3];
    const float* W2 = (const float*)d_in[4];
    const float* b2 = (const float*)d_in[5];
    float* out = (float*)d_out;

    int n = in_sizes[0] / 3;  // 20000
    int nblk = (n + 63) / 64; // 313

    char* ws = (char*)d_ws;
    size_t off = 0;
    auto alloc = [&](size_t bytes) {
        size_t o = off;
        off = (off + bytes + 255) & ~(size_t)255;
        return o;
    };
    unsigned short* grid1 = (unsigned short*)(ws + alloc((size_t)GRID_VOX * 2));
    float* h      = (float*)(ws + alloc((size_t)n * 64 * 4));     // 5.12 MB
    float* W2e    = (float*)(ws + alloc(64 * 4096 * 4));          // 1 MB
    unsigned short* Wpk1h = (unsigned short*)(ws + alloc(512 * 8 * 2));
    unsigned short* Wpk1l = (unsigned short*)(ws + alloc(512 * 8 * 2));
    unsigned short* Wpk2h = (unsigned short*)(ws + alloc(4096 * 8 * 2));
    unsigned short* Wpk2l = (unsigned short*)(ws + alloc(4096 * 8 * 2));
    int*   c1     = (int*)(ws + alloc((size_t)n * 9 * 4));        // c1[n]+c2s[8n]
    int*   c2s    = c1 + n;
    int*   p1     = (int*)(ws + alloc((size_t)n * CAP1 * 4));     // 2.56 MB
    int*   p2s    = (int*)(ws + alloc((size_t)n * 8 * CAP2S * 4)); // 5.12 MB

    setup_kernel<<<1474, 256, 0, stream>>>(W1, W2, (int4*)grid1, Wpk1h, Wpk1l,
                                           Wpk2h, Wpk2l, W2e);
    scatter_grid_kernel<<<(n + 255) / 256, 256, 0, stream>>>(coords, grid1, n);
    build_pairs_kernel<<<(n + 255) / 256, 256, 0, stream>>>(
        coords, grid1, c1, p1, c2s, p2s, n);

    conv1_fused_kernel<<<nblk, 256, 0, stream>>>(feats, W1, Wpk1h, Wpk1l, b1,
                                                 c1, p1, h, n);
    conv2_fused_kernel<<<dim3(nblk, 8), 256, 0, stream>>>(
        h, Wpk2h, Wpk2l, W2e, b2, c2s, p2s, out, n);
}